// Round 8
// baseline (296.180 us; speedup 1.0000x reference)
//
#include <hip/hip_runtime.h>
#include <math.h>

#define HW     17600   // 100*176 pixels
#define CD     256     // channels == D
#define LAG    5       // agents
#define NHEAD  8
#define DH     32
#define NT     3       // agent types

typedef short bf16x8 __attribute__((ext_vector_type(8)));
typedef float f32x4  __attribute__((ext_vector_type(4)));

// ---- bf16 helpers ----------------------------------------------------------
__device__ __forceinline__ float bflo(unsigned u) { return __uint_as_float(u << 16); }
__device__ __forceinline__ float bfhi(unsigned u) { return __uint_as_float(u & 0xffff0000u); }
__device__ __forceinline__ unsigned f2bf(float f) {
    unsigned u = __float_as_uint(f);
    return (u + 0x7fffu + ((u >> 16) & 1u)) >> 16;   // RNE
}
__device__ __forceinline__ unsigned pack2(float a, float b) {
    return f2bf(a) | (f2bf(b) << 16);
}

// ---------------------------------------------------------------------------
// convert_x: x fp32 -> bf16, elementwise. 8 elems/thread, 11000 blocks.
// ---------------------------------------------------------------------------
__global__ __launch_bounds__(256) void convert_x_kernel(
    const float* __restrict__ x, unsigned short* __restrict__ xb)
{
    const long i = ((long)blockIdx.x * 256 + threadIdx.x) * 8;
    float4 f0 = *(const float4*)(x + i);
    float4 f1 = *(const float4*)(x + i + 4);
    uint4 u;
    u.x = pack2(f0.x, f0.y); u.y = pack2(f0.z, f0.w);
    u.z = pack2(f1.x, f1.y); u.w = pack2(f1.z, f1.w);
    *(uint4*)(xb + i) = u;
}

// ---------------------------------------------------------------------------
// convert_w: W[k][n] fp32 -> Wt[n][k] bf16, 12 matrices (q0..2,k0..2,v0..2,a0..2)
// ---------------------------------------------------------------------------
__global__ __launch_bounds__(256) void convert_w_kernel(
    const float* __restrict__ Wq, const float* __restrict__ Wk,
    const float* __restrict__ Wv, const float* __restrict__ Wa,
    unsigned short* __restrict__ Wt)
{
    __shared__ float tile[64][65];
    const int mat = blockIdx.y;
    const int k0 = (blockIdx.x >> 2) * 64;
    const int n0 = (blockIdx.x & 3) * 64;
    const float* W;
    if      (mat < 3) W = Wq + (long)mat * 65536;
    else if (mat < 6) W = Wk + (long)(mat - 3) * 65536;
    else if (mat < 9) W = Wv + (long)(mat - 6) * 65536;
    else              W = Wa + (long)(mat - 9) * 65536;
    const int t = threadIdx.x;
#pragma unroll
    for (int r = 0; r < 16; ++r) {
        int idx = r * 256 + t;
        int row = idx >> 6, col = idx & 63;
        tile[row][col] = W[(long)(k0 + row) * 256 + n0 + col];
    }
    __syncthreads();
    unsigned short* dst = Wt + (long)mat * 65536;
#pragma unroll
    for (int r = 0; r < 16; ++r) {
        int idx = r * 256 + t;
        int row = idx >> 6, col = idx & 63;
        dst[(long)(n0 + row) * 256 + k0 + col] = (unsigned short)f2bf(tile[col][row]);
    }
}

// ---------------------------------------------------------------------------
// convert_rel: rel_att -> rattT bf16 [9][8][32 q][32 p] (transposed),
//              rel_msg -> rmsgT bf16 [9][8][32 c][32 p] (transposed).
// ---------------------------------------------------------------------------
__global__ __launch_bounds__(256) void convert_rel_kernel(
    const float* __restrict__ rel_att, const float* __restrict__ rel_msg,
    unsigned short* __restrict__ rattT, unsigned short* __restrict__ rmsgT)
{
    const long base = ((long)(blockIdx.x * NHEAD + blockIdx.y)) << 10;
    const int t = threadIdx.x;
#pragma unroll
    for (int i = 0; i < 4; ++i) {
        int idx = t * 4 + i;            // p*32+q
        int p = idx >> 5, q = idx & 31;
        rattT[base + q * 32 + p] = (unsigned short)f2bf(rel_att[base + idx]);
        rmsgT[base + q * 32 + p] = (unsigned short)f2bf(rel_msg[base + idx]);
    }
}

// ---------------------------------------------------------------------------
// MFMA GEMM core: Y[64 x 256] = A[M x 256] @ Wt^T + bias. A bf16.
// ---------------------------------------------------------------------------
template<bool YBF>
__device__ __forceinline__ void gemm_mfma_core(
    const unsigned short* __restrict__ Aptr, long lda,
    const unsigned short* __restrict__ Wt,
    const float* __restrict__ bias,
    void* __restrict__ Yptr, long ldy)
{
    __shared__ unsigned short As[64 * 64];
    __shared__ unsigned short Ws[256 * 64];

    const int t  = threadIdx.x;
    const int m0 = blockIdx.x * 64;
    const int w  = t >> 6;
    const int l  = t & 63;
    const int wr = w >> 1;
    const int wc = w & 1;
    const int fr = l & 15;
    const int ko = (l >> 4) << 3;

    const int srow = t >> 3;
    const int colu = (t & 7) << 3;
    const int scol = colu ^ ((srow & 7) << 3);
    const int axor = (fr & 7) << 3;

    f32x4 acc[2][8];
#pragma unroll
    for (int i = 0; i < 2; ++i)
#pragma unroll
        for (int j = 0; j < 8; ++j) {
            acc[i][j][0] = 0.f; acc[i][j][1] = 0.f;
            acc[i][j][2] = 0.f; acc[i][j][3] = 0.f;
        }

    for (int ks = 0; ks < 4; ++ks) {
        const int k0 = ks << 6;
        __syncthreads();
#pragma unroll
        for (int r = 0; r < 2; ++r) {
            int row = r * 32 + srow;
            const unsigned short* src = Aptr + (long)(m0 + row) * lda + k0 + colu;
            *(uint4*)(&As[row * 64 + scol]) = *(const uint4*)src;
        }
#pragma unroll
        for (int r = 0; r < 8; ++r) {
            int row = r * 32 + srow;
            *(uint4*)(&Ws[row * 64 + scol]) =
                *(const uint4*)(Wt + (long)row * 256 + k0 + colu);
        }
        __syncthreads();
#pragma unroll
        for (int kk = 0; kk < 2; ++kk) {
            const int fcol = ((kk << 5) | ko) ^ axor;
            bf16x8 a[2], b[8];
#pragma unroll
            for (int i = 0; i < 2; ++i)
                a[i] = *(const bf16x8*)(&As[(wr * 32 + i * 16 + fr) * 64 + fcol]);
#pragma unroll
            for (int j = 0; j < 8; ++j)
                b[j] = *(const bf16x8*)(&Ws[(wc * 128 + j * 16 + fr) * 64 + fcol]);
#pragma unroll
            for (int i = 0; i < 2; ++i)
#pragma unroll
                for (int j = 0; j < 8; ++j)
                    acc[i][j] = __builtin_amdgcn_mfma_f32_16x16x32_bf16(
                        a[i], b[j], acc[i][j], 0, 0, 0);
        }
    }

    const int fq = l >> 4;
#pragma unroll
    for (int j = 0; j < 8; ++j) {
        int col = wc * 128 + j * 16 + fr;
        float bz = bias[col];
#pragma unroll
        for (int i = 0; i < 2; ++i) {
            int rowb = m0 + wr * 32 + i * 16 + (fq << 2);
#pragma unroll
            for (int e = 0; e < 4; ++e) {
                float v = acc[i][j][e] + bz;
                if (YBF)
                    ((unsigned short*)Yptr)[(long)(rowb + e) * ldy + col] =
                        (unsigned short)f2bf(v);
                else
                    ((float*)Yptr)[(long)(rowb + e) * ldy + col] = v;
            }
        }
    }
}

// ---------------------------------------------------------------------------
// Kernel 1: q/k/v projections from bf16 x. grid (275, 1, 15)
// q -> [pix][5][256]; k,v -> [l][pix][256].
// ---------------------------------------------------------------------------
__global__ __launch_bounds__(256) void gemm_qkv_mfma(
    const unsigned short* __restrict__ xb, const float* __restrict__ pe,
    const unsigned short* __restrict__ Wt,
    const float* __restrict__ bq, const float* __restrict__ bk,
    const float* __restrict__ bv,
    unsigned short* __restrict__ qws, unsigned short* __restrict__ kws,
    unsigned short* __restrict__ vws)
{
    const int z = blockIdx.z;
    const int lag = z / 3, proj = z % 3;
    const int tpe = (int)pe[lag * 3 + 2];
    const unsigned short* A = xb + (long)lag * HW * CD;
    const unsigned short* Wm = Wt + (long)(proj * 3 + tpe) * 65536;
    const float* bias;
    unsigned short* Y;
    long ldy;
    if      (proj == 0) { bias = bq; Y = qws + (long)lag * CD; ldy = LAG * CD; }
    else if (proj == 1) { bias = bk; Y = kws + (long)lag * HW * CD; ldy = CD; }
    else                { bias = bv; Y = vws + (long)lag * HW * CD; ldy = CD; }
    bias += tpe * CD;
    gemm_mfma_core<true>(A, CD, Wm, bias, Y, ldy);
}

// ---------------------------------------------------------------------------
// Kernel 3: output projection. grid (275, 1, 5). A = aws [pix][5][256].
// ---------------------------------------------------------------------------
__global__ __launch_bounds__(256) void gemm_out_mfma(
    const unsigned short* __restrict__ aws, const float* __restrict__ pe,
    const unsigned short* __restrict__ Wt, const float* __restrict__ ba,
    float* __restrict__ out)
{
    const int lag = blockIdx.z;
    const int tpe = (int)pe[lag * 3 + 2];
    const unsigned short* A = aws + (long)lag * CD;
    const unsigned short* Wm = Wt + (long)(9 + tpe) * 65536;
    const float* bias = ba + tpe * CD;
    float* Y = out + (long)lag * HW * CD;
    gemm_mfma_core<false>(A, (long)LAG * CD, Wm, bias, Y, CD);
}

// ---------------------------------------------------------------------------
// Kernel 2 (FUSED attention v2): block = 64 pixels x 1 head, 256 thr = 4 waves.
// LDS = 21 KB (one 64px x 168 buffer, reused across phases via sigma-loop):
//  Phase A, per sigma: qt_s[i] = W_att[ty_i,s]^T q[i] via MFMA -> LDS;
//    barrier; partial logits for j with ty_j==s; barrier.
//  Softmax in registers.
//  Phase B, per sigma: vagg[i] -> LDS; barrier; out[i] += MFMA(vagg, rmsgT);
//    barrier.
// ---------------------------------------------------------------------------
#define VGROW 168   // 5*32 = 160 + 8 pad

__global__ __launch_bounds__(256) void attn_fused_kernel(
    const unsigned short* __restrict__ qws,    // [pix][5][256]
    const unsigned short* __restrict__ kws,    // [j][pix][256]
    const unsigned short* __restrict__ vws,    // [j][pix][256]
    const unsigned short* __restrict__ rattT,  // [9][8][32 q][32 p]
    const unsigned short* __restrict__ rmsgT,  // [9][8][32 c][32 p]
    const int* __restrict__ mask, const float* __restrict__ pe,
    unsigned short* __restrict__ aws)          // [pix][5][256]
{
    __shared__ unsigned short lds[4 * 16 * VGROW];   // 21504 B

    const int t    = threadIdx.x;
    const int w    = t >> 6;
    const int l    = t & 63;
    const int fr   = l & 15;
    const int fq   = l >> 4;
    const int m    = blockIdx.y;
    const int pix0 = blockIdx.x * 64;

    const int pl2   = t >> 2;          // 0..63 local pixel
    const int sub   = t & 3;           // octet index
    const int gpix2 = pix0 + pl2;
    const int wbase = w * 16 * VGROW;
    const int qtb   = wbase + (pl2 & 15) * VGROW;

    int ty[LAG];
#pragma unroll
    for (int i = 0; i < LAG; ++i) ty[i] = (int)pe[i * 3 + 2];
    bool pres[NT] = {false, false, false};
#pragma unroll
    for (int i = 0; i < LAG; ++i) {
        pres[0] = pres[0] || (ty[i] == 0);
        pres[1] = pres[1] || (ty[i] == 1);
        pres[2] = pres[2] || (ty[i] == 2);
    }

    // ---- early global loads: k, mask, q-frags ------------------------------
    uint4 kf[LAG];
    int mk[LAG];
#pragma unroll
    for (int j = 0; j < LAG; ++j) {
        kf[j] = *(const uint4*)(kws + ((long)j * HW + gpix2) * CD + m * DH + sub * 8);
        mk[j] = mask[gpix2 * LAG + j];
    }
    bf16x8 aq[LAG];
#pragma unroll
    for (int i = 0; i < LAG; ++i)
        aq[i] = *(const bf16x8*)(qws + (long)(pix0 + w * 16 + fr) * (LAG * CD)
                                 + i * CD + m * DH + fq * 8);

    float kx[LAG][8];
#pragma unroll
    for (int j = 0; j < LAG; ++j) {
        kx[j][0] = bflo(kf[j].x); kx[j][1] = bfhi(kf[j].x);
        kx[j][2] = bflo(kf[j].y); kx[j][3] = bfhi(kf[j].y);
        kx[j][4] = bflo(kf[j].z); kx[j][5] = bfhi(kf[j].z);
        kx[j][6] = bflo(kf[j].w); kx[j][7] = bfhi(kf[j].w);
    }

    // ---- phase A: per-sigma qt -> partial logits ---------------------------
    const float scale = 0.17677669529663687f;  // 32^-0.5
    float att[LAG][LAG];
    for (int sg = 0; sg < NT; ++sg) {
        if (!pres[sg]) continue;
        // qt_s via MFMA
#pragma unroll
        for (int i = 0; i < LAG; ++i) {
            const int e = ty[i] * NT + sg;
            const unsigned short* bb = rattT + ((long)(e * NHEAD + m) << 10);
            bf16x8 b0 = *(const bf16x8*)(bb + fr * 32 + fq * 8);
            bf16x8 b1 = *(const bf16x8*)(bb + (fr + 16) * 32 + fq * 8);
            f32x4 z = {0.f, 0.f, 0.f, 0.f};
            f32x4 d0 = __builtin_amdgcn_mfma_f32_16x16x32_bf16(aq[i], b0, z, 0, 0, 0);
            f32x4 d1 = __builtin_amdgcn_mfma_f32_16x16x32_bf16(aq[i], b1, z, 0, 0, 0);
#pragma unroll
            for (int e4 = 0; e4 < 4; ++e4) {
                const int idx = wbase + (fq * 4 + e4) * VGROW + i * 32;
                lds[idx + fr]      = (unsigned short)f2bf(d0[e4]);
                lds[idx + fr + 16] = (unsigned short)f2bf(d1[e4]);
            }
        }
        __syncthreads();
        // partial logits for j of this type
#pragma unroll
        for (int j = 0; j < LAG; ++j) {
            if (ty[j] != sg) continue;
#pragma unroll
            for (int i = 0; i < LAG; ++i) {
                uint4 qv = *(const uint4*)(&lds[qtb + i * 32 + sub * 8]);
                float part;
                part = bflo(qv.x) * kx[j][0];
                part = fmaf(bfhi(qv.x), kx[j][1], part);
                part = fmaf(bflo(qv.y), kx[j][2], part);
                part = fmaf(bfhi(qv.y), kx[j][3], part);
                part = fmaf(bflo(qv.z), kx[j][4], part);
                part = fmaf(bfhi(qv.z), kx[j][5], part);
                part = fmaf(bflo(qv.w), kx[j][6], part);
                part = fmaf(bfhi(qv.w), kx[j][7], part);
                part += __shfl_xor(part, 1);
                part += __shfl_xor(part, 2);
                att[i][j] = part * scale;
            }
        }
        __syncthreads();
    }

    // ---- softmax (registers) ----------------------------------------------
#pragma unroll
    for (int i = 0; i < LAG; ++i) {
        float mx = -INFINITY;
#pragma unroll
        for (int j = 0; j < LAG; ++j) {
            att[i][j] = mk[j] ? att[i][j] : -INFINITY;
            mx = fmaxf(mx, att[i][j]);
        }
        float ssum = 0.f;
#pragma unroll
        for (int j = 0; j < LAG; ++j) {
            att[i][j] = __expf(att[i][j] - mx);
            ssum += att[i][j];
        }
        float inv = 1.f / ssum;
#pragma unroll
        for (int j = 0; j < LAG; ++j) att[i][j] *= inv;
    }

    // ---- load + unpack v ---------------------------------------------------
    float vx[LAG][8];
#pragma unroll
    for (int j = 0; j < LAG; ++j) {
        uint4 vf = *(const uint4*)(vws + ((long)j * HW + gpix2) * CD + m * DH + sub * 8);
        vx[j][0] = bflo(vf.x); vx[j][1] = bfhi(vf.x);
        vx[j][2] = bflo(vf.y); vx[j][3] = bfhi(vf.y);
        vx[j][4] = bflo(vf.z); vx[j][5] = bfhi(vf.z);
        vx[j][6] = bflo(vf.w); vx[j][7] = bfhi(vf.w);
    }

    // ---- phase B: vagg + MFMA message transform ---------------------------
    f32x4 oacc[LAG][2];
#pragma unroll
    for (int i = 0; i < LAG; ++i)
#pragma unroll
        for (int c = 0; c < 2; ++c) {
            oacc[i][c][0] = 0.f; oacc[i][c][1] = 0.f;
            oacc[i][c][2] = 0.f; oacc[i][c][3] = 0.f;
        }

    for (int sg = 0; sg < NT; ++sg) {
        if (!pres[sg]) continue;
#pragma unroll
        for (int i = 0; i < LAG; ++i) {
            float vg[8] = {0.f,0.f,0.f,0.f,0.f,0.f,0.f,0.f};
#pragma unroll
            for (int j = 0; j < LAG; ++j) {
                float wj = (ty[j] == sg) ? att[i][j] : 0.f;
#pragma unroll
                for (int d = 0; d < 8; ++d) vg[d] = fmaf(wj, vx[j][d], vg[d]);
            }
            uint4 o;
            o.x = pack2(vg[0], vg[1]); o.y = pack2(vg[2], vg[3]);
            o.z = pack2(vg[4], vg[5]); o.w = pack2(vg[6], vg[7]);
            *(uint4*)(&lds[qtb + i * 32 + sub * 8]) = o;
        }
        __syncthreads();
#pragma unroll
        for (int i = 0; i < LAG; ++i) {
            bf16x8 a = *(const bf16x8*)(&lds[wbase + fr * VGROW + i * 32 + fq * 8]);
            const int e = ty[i] * NT + sg;
            const unsigned short* bb = rmsgT + ((long)(e * NHEAD + m) << 10);
            bf16x8 b0 = *(const bf16x8*)(bb + fr * 32 + fq * 8);
            bf16x8 b1 = *(const bf16x8*)(bb + (fr + 16) * 32 + fq * 8);
            oacc[i][0] = __builtin_amdgcn_mfma_f32_16x16x32_bf16(a, b0, oacc[i][0], 0, 0, 0);
            oacc[i][1] = __builtin_amdgcn_mfma_f32_16x16x32_bf16(a, b1, oacc[i][1], 0, 0, 0);
        }
        __syncthreads();
    }

    // ---- store: lane holds out[pix=fq*4+e][c=fr, fr+16] --------------------
#pragma unroll
    for (int i = 0; i < LAG; ++i) {
#pragma unroll
        for (int e4 = 0; e4 < 4; ++e4) {
            const long ob = (long)(pix0 + w * 16 + fq * 4 + e4) * (LAG * CD)
                            + i * CD + m * DH;
            aws[ob + fr]      = (unsigned short)f2bf(oacc[i][0][e4]);
            aws[ob + fr + 16] = (unsigned short)f2bf(oacc[i][1][e4]);
        }
    }
}

// ---------------------------------------------------------------------------
extern "C" void kernel_launch(void* const* d_in, const int* in_sizes, int n_in,
                              void* d_out, int out_size, void* d_ws, size_t ws_size,
                              hipStream_t stream) {
    const float* x    = (const float*)d_in[0];
    const int*   mask = (const int*)  d_in[1];
    const float* pe   = (const float*)d_in[2];
    const float* Wq   = (const float*)d_in[3];
    const float* bq   = (const float*)d_in[4];
    const float* Wk   = (const float*)d_in[5];
    const float* bk   = (const float*)d_in[6];
    const float* Wv   = (const float*)d_in[7];
    const float* bv   = (const float*)d_in[8];
    const float* Wa   = (const float*)d_in[9];
    const float* ba   = (const float*)d_in[10];
    const float* ratt = (const float*)d_in[11];
    const float* rmsg = (const float*)d_in[12];
    float* out = (float*)d_out;

    const size_t PLANE = (size_t)LAG * HW * CD;   // 22,528,000 elems

    unsigned short* qws   = (unsigned short*)d_ws;          // [pix][5][256]
    unsigned short* kws   = qws + PLANE;                    // [5][pix][256]
    unsigned short* vws   = kws + PLANE;
    unsigned short* aws   = vws + PLANE;                    // [pix][5][256]
    unsigned short* xb    = aws + PLANE;                    // [5][pix][256]
    unsigned short* Wt    = xb + PLANE;     // 786,432 elems
    unsigned short* rattT = Wt + 786432;    // 73,728 elems
    unsigned short* rmsgT = rattT + 73728;  // 73,728 elems
    // total ~227 MB

    convert_w_kernel<<<dim3(16, 12), 256, 0, stream>>>(Wq, Wk, Wv, Wa, Wt);
    convert_rel_kernel<<<dim3(9, 8), 256, 0, stream>>>(ratt, rmsg, rattT, rmsgT);
    convert_x_kernel<<<dim3(11000), 256, 0, stream>>>(x, xb);

    gemm_qkv_mfma<<<dim3(HW / 64, 1, LAG * 3), 256, 0, stream>>>(
        xb, pe, Wt, bq, bk, bv, qws, kws, vws);

    attn_fused_kernel<<<dim3(HW / 64, NHEAD), 256, 0, stream>>>(
        qws, kws, vws, rattT, rmsgT, mask, pe, aws);

    gemm_out_mfma<<<dim3(HW / 64, 1, LAG), 256, 0, stream>>>(aws, pe, Wt, ba, out);
}

// Round 9
// 212.571 us; speedup vs baseline: 1.3933x; 1.3933x over previous
//
#include <hip/hip_runtime.h>
#include <math.h>

#define HW     17600   // 100*176 pixels
#define CD     256     // channels == D
#define LAG    5       // agents
#define NHEAD  8
#define DH     32
#define NT     3       // agent types

typedef short bf16x8 __attribute__((ext_vector_type(8)));
typedef float f32x4  __attribute__((ext_vector_type(4)));

// ---- bf16 helpers ----------------------------------------------------------
__device__ __forceinline__ float bflo(unsigned u) { return __uint_as_float(u << 16); }
__device__ __forceinline__ float bfhi(unsigned u) { return __uint_as_float(u & 0xffff0000u); }
__device__ __forceinline__ unsigned f2bf(float f) {
    unsigned u = __float_as_uint(f);
    return (u + 0x7fffu + ((u >> 16) & 1u)) >> 16;   // RNE
}
__device__ __forceinline__ unsigned pack2(float a, float b) {
    return f2bf(a) | (f2bf(b) << 16);
}

// ---------------------------------------------------------------------------
// convert_w: W[k][n] fp32 -> Wt[n][k] bf16, 12 matrices (q0..2,k0..2,v0..2,a0..2)
// ---------------------------------------------------------------------------
__global__ __launch_bounds__(256) void convert_w_kernel(
    const float* __restrict__ Wq, const float* __restrict__ Wk,
    const float* __restrict__ Wv, const float* __restrict__ Wa,
    unsigned short* __restrict__ Wt)
{
    __shared__ float tile[64][65];
    const int mat = blockIdx.y;
    const int k0 = (blockIdx.x >> 2) * 64;
    const int n0 = (blockIdx.x & 3) * 64;
    const float* W;
    if      (mat < 3) W = Wq + (long)mat * 65536;
    else if (mat < 6) W = Wk + (long)(mat - 3) * 65536;
    else if (mat < 9) W = Wv + (long)(mat - 6) * 65536;
    else              W = Wa + (long)(mat - 9) * 65536;
    const int t = threadIdx.x;
#pragma unroll
    for (int r = 0; r < 16; ++r) {
        int idx = r * 256 + t;
        int row = idx >> 6, col = idx & 63;
        tile[row][col] = W[(long)(k0 + row) * 256 + n0 + col];
    }
    __syncthreads();
    unsigned short* dst = Wt + (long)mat * 65536;
#pragma unroll
    for (int r = 0; r < 16; ++r) {
        int idx = r * 256 + t;
        int row = idx >> 6, col = idx & 63;
        dst[(long)(n0 + row) * 256 + k0 + col] = (unsigned short)f2bf(tile[col][row]);
    }
}

// ---------------------------------------------------------------------------
// convert_rel: rel_att -> rattT bf16 [9][8][32 q][32 p] (transposed),
//              rel_msg -> rmsgT bf16 [9][8][32 c][32 p] (transposed).
// ---------------------------------------------------------------------------
__global__ __launch_bounds__(256) void convert_rel_kernel(
    const float* __restrict__ rel_att, const float* __restrict__ rel_msg,
    unsigned short* __restrict__ rattT, unsigned short* __restrict__ rmsgT)
{
    const long base = ((long)(blockIdx.x * NHEAD + blockIdx.y)) << 10;
    const int t = threadIdx.x;
#pragma unroll
    for (int i = 0; i < 4; ++i) {
        int idx = t * 4 + i;            // p*32+q
        int p = idx >> 5, q = idx & 31;
        rattT[base + q * 32 + p] = (unsigned short)f2bf(rel_att[base + idx]);
        rmsgT[base + q * 32 + p] = (unsigned short)f2bf(rel_msg[base + idx]);
    }
}

// ---------------------------------------------------------------------------
// MFMA GEMM core: Y[64 x 256] = A[M x 256] @ Wt^T + bias.
// A fp32 (converted during staging, AF32=true) or bf16.
// LDS XOR-swizzled: col ^= (row&7)<<3 on store and fragment read.
// ---------------------------------------------------------------------------
template<bool AF32, bool YBF>
__device__ __forceinline__ void gemm_mfma_core(
    const void* __restrict__ Aptr, long lda,
    const unsigned short* __restrict__ Wt,
    const float* __restrict__ bias,
    void* __restrict__ Yptr, long ldy)
{
    __shared__ unsigned short As[64 * 64];
    __shared__ unsigned short Ws[256 * 64];

    const int t  = threadIdx.x;
    const int m0 = blockIdx.x * 64;
    const int w  = t >> 6;
    const int l  = t & 63;
    const int wr = w >> 1;
    const int wc = w & 1;
    const int fr = l & 15;
    const int ko = (l >> 4) << 3;

    const int srow = t >> 3;
    const int colu = (t & 7) << 3;
    const int scol = colu ^ ((srow & 7) << 3);
    const int axor = (fr & 7) << 3;

    f32x4 acc[2][8];
#pragma unroll
    for (int i = 0; i < 2; ++i)
#pragma unroll
        for (int j = 0; j < 8; ++j) {
            acc[i][j][0] = 0.f; acc[i][j][1] = 0.f;
            acc[i][j][2] = 0.f; acc[i][j][3] = 0.f;
        }

    for (int ks = 0; ks < 4; ++ks) {
        const int k0 = ks << 6;
        __syncthreads();
#pragma unroll
        for (int r = 0; r < 2; ++r) {
            int row = r * 32 + srow;
            if (AF32) {
                const float* src = (const float*)Aptr + (long)(m0 + row) * lda + k0 + colu;
                float4 f0 = *(const float4*)src;
                float4 f1 = *(const float4*)(src + 4);
                uint4 u;
                u.x = pack2(f0.x, f0.y); u.y = pack2(f0.z, f0.w);
                u.z = pack2(f1.x, f1.y); u.w = pack2(f1.z, f1.w);
                *(uint4*)(&As[row * 64 + scol]) = u;
            } else {
                const unsigned short* src =
                    (const unsigned short*)Aptr + (long)(m0 + row) * lda + k0 + colu;
                *(uint4*)(&As[row * 64 + scol]) = *(const uint4*)src;
            }
        }
#pragma unroll
        for (int r = 0; r < 8; ++r) {
            int row = r * 32 + srow;
            *(uint4*)(&Ws[row * 64 + scol]) =
                *(const uint4*)(Wt + (long)row * 256 + k0 + colu);
        }
        __syncthreads();
#pragma unroll
        for (int kk = 0; kk < 2; ++kk) {
            const int fcol = ((kk << 5) | ko) ^ axor;
            bf16x8 a[2], b[8];
#pragma unroll
            for (int i = 0; i < 2; ++i)
                a[i] = *(const bf16x8*)(&As[(wr * 32 + i * 16 + fr) * 64 + fcol]);
#pragma unroll
            for (int j = 0; j < 8; ++j)
                b[j] = *(const bf16x8*)(&Ws[(wc * 128 + j * 16 + fr) * 64 + fcol]);
#pragma unroll
            for (int i = 0; i < 2; ++i)
#pragma unroll
                for (int j = 0; j < 8; ++j)
                    acc[i][j] = __builtin_amdgcn_mfma_f32_16x16x32_bf16(
                        a[i], b[j], acc[i][j], 0, 0, 0);
        }
    }

    const int fq = l >> 4;
#pragma unroll
    for (int j = 0; j < 8; ++j) {
        int col = wc * 128 + j * 16 + fr;
        float bz = bias[col];
#pragma unroll
        for (int i = 0; i < 2; ++i) {
            int rowb = m0 + wr * 32 + i * 16 + (fq << 2);
#pragma unroll
            for (int e = 0; e < 4; ++e) {
                float v = acc[i][j][e] + bz;
                if (YBF)
                    ((unsigned short*)Yptr)[(long)(rowb + e) * ldy + col] =
                        (unsigned short)f2bf(v);
                else
                    ((float*)Yptr)[(long)(rowb + e) * ldy + col] = v;
            }
        }
    }
}

// ---------------------------------------------------------------------------
// Kernel 1: fused q/k/v projections. grid (275, 1, 5): z = agent.
// proj loop INSIDE the block: the 64-row x-panel (64 KB) is read 3x by the
// same block -> 2nd/3rd passes are L2 hits; x HBM fetch ~1x instead of 3x.
// q -> [pix][5][256]; k,v -> [l][pix][256].
// ---------------------------------------------------------------------------
__global__ __launch_bounds__(256) void gemm_qkv_mfma(
    const float* __restrict__ x, const float* __restrict__ pe,
    const unsigned short* __restrict__ Wt,
    const float* __restrict__ bq, const float* __restrict__ bk,
    const float* __restrict__ bv,
    unsigned short* __restrict__ qws, unsigned short* __restrict__ kws,
    unsigned short* __restrict__ vws)
{
    const int lag = blockIdx.z;
    const int tpe = (int)pe[lag * 3 + 2];
    const float* A = x + (long)lag * HW * CD;

#pragma unroll 1
    for (int proj = 0; proj < 3; ++proj) {
        const unsigned short* Wm = Wt + (long)(proj * 3 + tpe) * 65536;
        const float* bias;
        unsigned short* Y;
        long ldy;
        if      (proj == 0) { bias = bq; Y = qws + (long)lag * CD; ldy = LAG * CD; }
        else if (proj == 1) { bias = bk; Y = kws + (long)lag * HW * CD; ldy = CD; }
        else                { bias = bv; Y = vws + (long)lag * HW * CD; ldy = CD; }
        bias += tpe * CD;
        gemm_mfma_core<true, true>(A, CD, Wm, bias, Y, ldy);
        __syncthreads();
    }
}

// ---------------------------------------------------------------------------
// Kernel 3: output projection. grid (275, 1, 5). A = aws [pix][5][256].
// ---------------------------------------------------------------------------
__global__ __launch_bounds__(256) void gemm_out_mfma(
    const unsigned short* __restrict__ aws, const float* __restrict__ pe,
    const unsigned short* __restrict__ Wt, const float* __restrict__ ba,
    float* __restrict__ out)
{
    const int lag = blockIdx.z;
    const int tpe = (int)pe[lag * 3 + 2];
    const unsigned short* A = aws + (long)lag * CD;
    const unsigned short* Wm = Wt + (long)(9 + tpe) * 65536;
    const float* bias = ba + tpe * CD;
    float* Y = out + (long)lag * HW * CD;
    gemm_mfma_core<false, false>(A, (long)LAG * CD, Wm, bias, Y, CD);
}

// ---------------------------------------------------------------------------
// Kernel 2 (FUSED attention v2): block = 64 pixels x 1 head, 256 thr = 4 waves.
// LDS = 21 KB, reused across phases via sigma-loop.
// ---------------------------------------------------------------------------
#define VGROW 168   // 5*32 = 160 + 8 pad

__global__ __launch_bounds__(256) void attn_fused_kernel(
    const unsigned short* __restrict__ qws,    // [pix][5][256]
    const unsigned short* __restrict__ kws,    // [j][pix][256]
    const unsigned short* __restrict__ vws,    // [j][pix][256]
    const unsigned short* __restrict__ rattT,  // [9][8][32 q][32 p]
    const unsigned short* __restrict__ rmsgT,  // [9][8][32 c][32 p]
    const int* __restrict__ mask, const float* __restrict__ pe,
    unsigned short* __restrict__ aws)          // [pix][5][256]
{
    __shared__ unsigned short lds[4 * 16 * VGROW];   // 21504 B

    const int t    = threadIdx.x;
    const int w    = t >> 6;
    const int l    = t & 63;
    const int fr   = l & 15;
    const int fq   = l >> 4;
    const int m    = blockIdx.y;
    const int pix0 = blockIdx.x * 64;

    const int pl2   = t >> 2;          // 0..63 local pixel
    const int sub   = t & 3;           // octet index
    const int gpix2 = pix0 + pl2;
    const int wbase = w * 16 * VGROW;
    const int qtb   = wbase + (pl2 & 15) * VGROW;

    int ty[LAG];
#pragma unroll
    for (int i = 0; i < LAG; ++i) ty[i] = (int)pe[i * 3 + 2];
    bool pres[NT] = {false, false, false};
#pragma unroll
    for (int i = 0; i < LAG; ++i) {
        pres[0] = pres[0] || (ty[i] == 0);
        pres[1] = pres[1] || (ty[i] == 1);
        pres[2] = pres[2] || (ty[i] == 2);
    }

    // ---- early global loads: k, mask, q-frags ------------------------------
    uint4 kf[LAG];
    int mk[LAG];
#pragma unroll
    for (int j = 0; j < LAG; ++j) {
        kf[j] = *(const uint4*)(kws + ((long)j * HW + gpix2) * CD + m * DH + sub * 8);
        mk[j] = mask[gpix2 * LAG + j];
    }
    bf16x8 aq[LAG];
#pragma unroll
    for (int i = 0; i < LAG; ++i)
        aq[i] = *(const bf16x8*)(qws + (long)(pix0 + w * 16 + fr) * (LAG * CD)
                                 + i * CD + m * DH + fq * 8);

    float kx[LAG][8];
#pragma unroll
    for (int j = 0; j < LAG; ++j) {
        kx[j][0] = bflo(kf[j].x); kx[j][1] = bfhi(kf[j].x);
        kx[j][2] = bflo(kf[j].y); kx[j][3] = bfhi(kf[j].y);
        kx[j][4] = bflo(kf[j].z); kx[j][5] = bfhi(kf[j].z);
        kx[j][6] = bflo(kf[j].w); kx[j][7] = bfhi(kf[j].w);
    }

    // ---- phase A: per-sigma qt -> partial logits ---------------------------
    const float scale = 0.17677669529663687f;  // 32^-0.5
    float att[LAG][LAG];
    for (int sg = 0; sg < NT; ++sg) {
        if (!pres[sg]) continue;
#pragma unroll
        for (int i = 0; i < LAG; ++i) {
            const int e = ty[i] * NT + sg;
            const unsigned short* bb = rattT + ((long)(e * NHEAD + m) << 10);
            bf16x8 b0 = *(const bf16x8*)(bb + fr * 32 + fq * 8);
            bf16x8 b1 = *(const bf16x8*)(bb + (fr + 16) * 32 + fq * 8);
            f32x4 z = {0.f, 0.f, 0.f, 0.f};
            f32x4 d0 = __builtin_amdgcn_mfma_f32_16x16x32_bf16(aq[i], b0, z, 0, 0, 0);
            f32x4 d1 = __builtin_amdgcn_mfma_f32_16x16x32_bf16(aq[i], b1, z, 0, 0, 0);
#pragma unroll
            for (int e4 = 0; e4 < 4; ++e4) {
                const int idx = wbase + (fq * 4 + e4) * VGROW + i * 32;
                lds[idx + fr]      = (unsigned short)f2bf(d0[e4]);
                lds[idx + fr + 16] = (unsigned short)f2bf(d1[e4]);
            }
        }
        __syncthreads();
#pragma unroll
        for (int j = 0; j < LAG; ++j) {
            if (ty[j] != sg) continue;
#pragma unroll
            for (int i = 0; i < LAG; ++i) {
                uint4 qv = *(const uint4*)(&lds[qtb + i * 32 + sub * 8]);
                float part;
                part = bflo(qv.x) * kx[j][0];
                part = fmaf(bfhi(qv.x), kx[j][1], part);
                part = fmaf(bflo(qv.y), kx[j][2], part);
                part = fmaf(bfhi(qv.y), kx[j][3], part);
                part = fmaf(bflo(qv.z), kx[j][4], part);
                part = fmaf(bfhi(qv.z), kx[j][5], part);
                part = fmaf(bflo(qv.w), kx[j][6], part);
                part = fmaf(bfhi(qv.w), kx[j][7], part);
                part += __shfl_xor(part, 1);
                part += __shfl_xor(part, 2);
                att[i][j] = part * scale;
            }
        }
        __syncthreads();
    }

    // ---- softmax (registers) ----------------------------------------------
#pragma unroll
    for (int i = 0; i < LAG; ++i) {
        float mx = -INFINITY;
#pragma unroll
        for (int j = 0; j < LAG; ++j) {
            att[i][j] = mk[j] ? att[i][j] : -INFINITY;
            mx = fmaxf(mx, att[i][j]);
        }
        float ssum = 0.f;
#pragma unroll
        for (int j = 0; j < LAG; ++j) {
            att[i][j] = __expf(att[i][j] - mx);
            ssum += att[i][j];
        }
        float inv = 1.f / ssum;
#pragma unroll
        for (int j = 0; j < LAG; ++j) att[i][j] *= inv;
    }

    // ---- load + unpack v ---------------------------------------------------
    float vx[LAG][8];
#pragma unroll
    for (int j = 0; j < LAG; ++j) {
        uint4 vf = *(const uint4*)(vws + ((long)j * HW + gpix2) * CD + m * DH + sub * 8);
        vx[j][0] = bflo(vf.x); vx[j][1] = bfhi(vf.x);
        vx[j][2] = bflo(vf.y); vx[j][3] = bfhi(vf.y);
        vx[j][4] = bflo(vf.z); vx[j][5] = bfhi(vf.z);
        vx[j][6] = bflo(vf.w); vx[j][7] = bfhi(vf.w);
    }

    // ---- phase B: vagg + MFMA message transform ---------------------------
    f32x4 oacc[LAG][2];
#pragma unroll
    for (int i = 0; i < LAG; ++i)
#pragma unroll
        for (int c = 0; c < 2; ++c) {
            oacc[i][c][0] = 0.f; oacc[i][c][1] = 0.f;
            oacc[i][c][2] = 0.f; oacc[i][c][3] = 0.f;
        }

    for (int sg = 0; sg < NT; ++sg) {
        if (!pres[sg]) continue;
#pragma unroll
        for (int i = 0; i < LAG; ++i) {
            float vg[8] = {0.f,0.f,0.f,0.f,0.f,0.f,0.f,0.f};
#pragma unroll
            for (int j = 0; j < LAG; ++j) {
                float wj = (ty[j] == sg) ? att[i][j] : 0.f;
#pragma unroll
                for (int d = 0; d < 8; ++d) vg[d] = fmaf(wj, vx[j][d], vg[d]);
            }
            uint4 o;
            o.x = pack2(vg[0], vg[1]); o.y = pack2(vg[2], vg[3]);
            o.z = pack2(vg[4], vg[5]); o.w = pack2(vg[6], vg[7]);
            *(uint4*)(&lds[qtb + i * 32 + sub * 8]) = o;
        }
        __syncthreads();
#pragma unroll
        for (int i = 0; i < LAG; ++i) {
            bf16x8 a = *(const bf16x8*)(&lds[wbase + fr * VGROW + i * 32 + fq * 8]);
            const int e = ty[i] * NT + sg;
            const unsigned short* bb = rmsgT + ((long)(e * NHEAD + m) << 10);
            bf16x8 b0 = *(const bf16x8*)(bb + fr * 32 + fq * 8);
            bf16x8 b1 = *(const bf16x8*)(bb + (fr + 16) * 32 + fq * 8);
            oacc[i][0] = __builtin_amdgcn_mfma_f32_16x16x32_bf16(a, b0, oacc[i][0], 0, 0, 0);
            oacc[i][1] = __builtin_amdgcn_mfma_f32_16x16x32_bf16(a, b1, oacc[i][1], 0, 0, 0);
        }
        __syncthreads();
    }

    // ---- store: lane holds out[pix=fq*4+e][c=fr, fr+16] --------------------
#pragma unroll
    for (int i = 0; i < LAG; ++i) {
#pragma unroll
        for (int e4 = 0; e4 < 4; ++e4) {
            const long ob = (long)(pix0 + w * 16 + fq * 4 + e4) * (LAG * CD)
                            + i * CD + m * DH;
            aws[ob + fr]      = (unsigned short)f2bf(oacc[i][0][e4]);
            aws[ob + fr + 16] = (unsigned short)f2bf(oacc[i][1][e4]);
        }
    }
}

// ---------------------------------------------------------------------------
extern "C" void kernel_launch(void* const* d_in, const int* in_sizes, int n_in,
                              void* d_out, int out_size, void* d_ws, size_t ws_size,
                              hipStream_t stream) {
    const float* x    = (const float*)d_in[0];
    const int*   mask = (const int*)  d_in[1];
    const float* pe   = (const float*)d_in[2];
    const float* Wq   = (const float*)d_in[3];
    const float* bq   = (const float*)d_in[4];
    const float* Wk   = (const float*)d_in[5];
    const float* bk   = (const float*)d_in[6];
    const float* Wv   = (const float*)d_in[7];
    const float* bv   = (const float*)d_in[8];
    const float* Wa   = (const float*)d_in[9];
    const float* ba   = (const float*)d_in[10];
    const float* ratt = (const float*)d_in[11];
    const float* rmsg = (const float*)d_in[12];
    float* out = (float*)d_out;

    const size_t PLANE = (size_t)LAG * HW * CD;   // 22,528,000 elems

    unsigned short* qws   = (unsigned short*)d_ws;          // [pix][5][256]
    unsigned short* kws   = qws + PLANE;                    // [5][pix][256]
    unsigned short* vws   = kws + PLANE;
    unsigned short* aws   = vws + PLANE;                    // [pix][5][256]
    unsigned short* Wt    = aws + PLANE;    // 786,432 elems
    unsigned short* rattT = Wt + 786432;    // 73,728 elems
    unsigned short* rmsgT = rattT + 73728;  // 73,728 elems
    // total ~182 MB

    convert_w_kernel<<<dim3(16, 12), 256, 0, stream>>>(Wq, Wk, Wv, Wa, Wt);
    convert_rel_kernel<<<dim3(9, 8), 256, 0, stream>>>(ratt, rmsg, rattT, rmsgT);

    gemm_qkv_mfma<<<dim3(HW / 64, 1, LAG), 256, 0, stream>>>(
        x, pe, Wt, bq, bk, bv, qws, kws, vws);

    attn_fused_kernel<<<dim3(HW / 64, NHEAD), 256, 0, stream>>>(
        qws, kws, vws, rattT, rmsgT, mask, pe, aws);

    gemm_out_mfma<<<dim3(HW / 64, 1, LAG), 256, 0, stream>>>(aws, pe, Wt, ba, out);
}